// Round 7
// baseline (1307.569 us; speedup 1.0000x reference)
//
#include <hip/hip_runtime.h>
#include <hip/hip_bf16.h>

// ---------------------------------------------------------------------------
// attention via: E = exp(QK^T/32) (bf16), inv[r] = 1/sum_k E[r,k] (per-wave
// partials), O = diag(inv)*E*V.
// GEMM1 (E = QK^T): bk32 kernel — BM=BN=256, BK=32, LDS row-paired A|B
// layout (row r = [A-row r 64B | B-row r 64B], stride 128B, 8 slots, verified
// XOR swizzle slot=(base+g)^(r&7)). 2 buffers x 32KB = 64KB -> 2 blocks/CU
// (16 waves/CU): cross-block overlap feeds LDS + MFMA pipes concurrently
// (m114 mechanism). 2 phases/tile, 1 stage-unit/phase, VGPR capped 128 via
// __launch_bounds__(512,4). Supertile XCD decode kept (FETCH 96MB verified).
// GEMM2 (O = E V): unchanged 8-phase r5 kernel (BM=128, ~131us).
// ws: [0,128MB)=E ; [128MB,144MB)=V^T ; [144MB,148MB)=partials ; then inv.
// ---------------------------------------------------------------------------

typedef __bf16 bf16x8 __attribute__((ext_vector_type(8)));
typedef float f32x4 __attribute__((ext_vector_type(4)));
typedef const __attribute__((address_space(1))) unsigned int* as1p;
typedef __attribute__((address_space(3))) unsigned int* as3p;
typedef unsigned short u16;

__device__ __forceinline__ u16 f2bf(float x) {
  unsigned u = __float_as_uint(x);
  u += 0x7fffu + ((u >> 16) & 1u);
  return (u16)(u >> 16);
}
__device__ __forceinline__ float bf2f(u16 b) { return __uint_as_float(((unsigned)b) << 16); }
__device__ __forceinline__ unsigned pack2(float lo, float hi) {
  return (unsigned)f2bf(lo) | ((unsigned)f2bf(hi) << 16);
}

#define BAR()   do { __builtin_amdgcn_s_barrier(); asm volatile("" ::: "memory"); } while (0)
#define LGKM0() do { asm volatile("s_waitcnt lgkmcnt(0)" ::: "memory"); __builtin_amdgcn_sched_barrier(0); } while (0)
#define VM(n)   do { asm volatile("s_waitcnt vmcnt(" #n ")" ::: "memory"); __builtin_amdgcn_sched_barrier(0); } while (0)

// --------------------------- f32 -> bf16 convert ---------------------------
__global__ __launch_bounds__(256) void cvt_bf16(const float* __restrict__ in,
                                                unsigned short* __restrict__ out) {
  const size_t i = (size_t)blockIdx.x * 256 + threadIdx.x;
  const float4* p = (const float4*)in + i * 2;
  float4 a = p[0], b = p[1];
  uint4 o;
  o.x = pack2(a.x, a.y);
  o.y = pack2(a.z, a.w);
  o.z = pack2(b.x, b.y);
  o.w = pack2(b.z, b.w);
  ((uint4*)out)[i] = o;
}

// ------------- V [8192,1024] f32 -> V^T [1024,8192] bf16 -------------------
__global__ __launch_bounds__(256) void transpose_bf16(const float* __restrict__ V,
                                                      unsigned short* __restrict__ VT) {
  __shared__ float t[64][65];
  const int rb = blockIdx.x * 64;
  const int cb = blockIdx.y * 64;
  const int tid = threadIdx.x;
#pragma unroll
  for (int it = 0; it < 4; ++it) {
    int r = it * 16 + (tid >> 4);
    int c = (tid & 15) * 4;
    float4 x = *(const float4*)(V + (size_t)(rb + r) * 1024 + cb + c);
    t[r][c] = x.x; t[r][c + 1] = x.y; t[r][c + 2] = x.z; t[r][c + 3] = x.w;
  }
  __syncthreads();
  const int j = tid & 63;
  const int c0 = (tid >> 6) * 16;
#pragma unroll
  for (int i = 0; i < 16; ++i) {
    int c = c0 + i;
    VT[(size_t)(cb + c) * 8192 + rb + j] = f2bf(t[j][c]);
  }
}

// --------------- GEMM1: E = exp(Q K^T / 32), BK=32, 2 blocks/CU ------------
// C[8192,8192] bf16 = exp((A[8192,1024] B[8192,1024]^T) * scale).
// 512 thr (8 waves 2Mx4N, per-wave 128x64). LDS: [2 bufs][256 rows][128B],
// row r = A-row/B-row pair; slot s holds chunk s^(r&7) (chunks 0-3 = A k-16B
// pieces, 4-7 = B). Per tile: ph0 {read A0-3+B0-3, stage u0(t+1)}, ph1
// {read A4-7, stage u1(t+1), drain}. Writes per-wave row partials.
__global__ __launch_bounds__(512, 4) void gemm1_bk32(const u16* __restrict__ A,
                                                     const u16* __restrict__ B,
                                                     u16* __restrict__ C,
                                                     float* __restrict__ partials,
                                                     float scale) {
  constexpr int K = 1024, LDC = 8192, NT = 32;
  __shared__ __align__(1024) char smem[2 * 32768];

  const int tid = threadIdx.x;
  const int lane = tid & 63, wave = tid >> 6;
  const int wr = wave >> 2, wc = wave & 3;
  const int lan15 = lane & 15, g = lane >> 4, l7 = lane & 7;

  // T1 bijective XCD swizzle + 16x8 supertile per XCD chunk (FETCH-verified)
  const int nwg = gridDim.x;  // 1024
  const int wg = (blockIdx.x & 7) * (nwg >> 3) + (blockIdx.x >> 3);
  const int rr = wg & 255;
  const int bm0 = (rr >> 3) * 256;
  const int bn0 = (((wg >> 8) << 3) | (rr & 7)) * 256;

  // staging source: fixed per thread. LDS row r0=tid>>3, slot tid&7 holds
  // chunk c = (tid&7)^(r0&7); c<4 -> A row bm0+r, k-chunk c; else B, c-4.
  const int r0 = tid >> 3;
  const int c = (tid & 7) ^ (r0 & 7);
  const u16* gsrc = (c < 4) ? (A + (size_t)(bm0 + r0) * K + c * 8)
                            : (B + (size_t)(bn0 + r0) * K + (c - 4) * 8);
  const int dst0 = tid * 16;

  // fragment reads: A slots base 0, B slots base 4, XOR l7 (= row&7)
  const int abase = (wr * 128 + lan15) * 128 + ((0 + g) ^ l7) * 16;
  const int bbase = (wc * 64 + lan15) * 128 + ((4 + g) ^ l7) * 16;

  f32x4 acc[8][4];
#pragma unroll
  for (int m = 0; m < 8; ++m)
#pragma unroll
    for (int n = 0; n < 4; ++n) acc[m][n] = f32x4{0.f, 0.f, 0.f, 0.f};

  auto ISSUE = [&](int t, int u) {  // unit u: batches 2u, 2u+1 (64 rows each)
    char* nb = smem + (t & 1) * 32768;
#pragma unroll
    for (int s = 0; s < 2; ++s) {
      const int j = 2 * u + s;
      __builtin_amdgcn_global_load_lds((as1p)(gsrc + (size_t)j * 64 * K + t * 32),
                                       (as3p)(nb + j * 8192 + dst0), 16, 0, 0);
    }
  };

  // prologue: tile 0 fully staged
  ISSUE(0, 0); ISSUE(0, 1);
  VM(0);
  BAR();

  bf16x8 a[4], b[4];
  for (int t = 0; t < NT; ++t) {
    const char* bp = smem + (t & 1) * 32768;
    // ---- ph0: read A mf0-3 + B all; stage u0(t+1) [targets buf(t-1): safe]
#pragma unroll
    for (int m = 0; m < 4; ++m) a[m] = *(const bf16x8*)(bp + abase + m * 2048);
#pragma unroll
    for (int n = 0; n < 4; ++n) b[n] = *(const bf16x8*)(bp + bbase + n * 2048);
    if (t + 1 < NT) ISSUE(t + 1, 0);
    BAR();
    __builtin_amdgcn_s_setprio(1);
#pragma unroll
    for (int m = 0; m < 4; ++m)
#pragma unroll
      for (int n = 0; n < 4; ++n)
        acc[m][n] = __builtin_amdgcn_mfma_f32_16x16x32_bf16(a[m], b[n], acc[m][n], 0, 0, 0);
    __builtin_amdgcn_s_setprio(0);
    BAR();
    // ---- ph1: read A mf4-7; stage u1(t+1); drain t+1 loads before close
#pragma unroll
    for (int m = 0; m < 4; ++m) a[m] = *(const bf16x8*)(bp + abase + (4 + m) * 2048);
    if (t + 1 < NT) ISSUE(t + 1, 1);
    BAR();
    __builtin_amdgcn_s_setprio(1);
#pragma unroll
    for (int m = 0; m < 4; ++m)
#pragma unroll
      for (int n = 0; n < 4; ++n)
        acc[4 + m][n] = __builtin_amdgcn_mfma_f32_16x16x32_bf16(a[m], b[n], acc[4 + m][n], 0, 0, 0);
    __builtin_amdgcn_s_setprio(0);
    if (t + 1 < NT) VM(0);
    BAR();
  }

  // ---- epilogue: C = bf16 exp(acc*scale); per-wave row partials.
  // C/D map: col = lane&15, row = (lane>>4)*4 + reg
  const int c0 = bn0 + wc * 64 + lan15;
  const int cb4 = (bn0 >> 8) * 4 + wc;
#pragma unroll
  for (int m = 0; m < 8; ++m)
#pragma unroll
    for (int r = 0; r < 4; ++r) {
      const int row = bm0 + wr * 128 + m * 16 + g * 4 + r;
      float part = 0.f;
#pragma unroll
      for (int n = 0; n < 4; ++n) {
        float v = __expf(acc[m][n][r] * scale);
        C[(size_t)row * LDC + c0 + n * 16] = f2bf(v);
        part += v;
      }
      part += __shfl_xor(part, 1, 64);
      part += __shfl_xor(part, 2, 64);
      part += __shfl_xor(part, 4, 64);
      part += __shfl_xor(part, 8, 64);
      if (lan15 == 0) partials[(size_t)row * 128 + cb4] = part;
    }
}

// ----------------------- GEMM2: 8-phase NT GEMM (r5, unchanged) ------------
// C[M,N](ldc) = A[M,K]*B[N,K]^T, BN=256, BM=128. 512 threads, 8 waves.
// grid 256 = 4 bn x 64 bm, bm fastest (VT quadrant L2-resident per XCD).
// C = f32 acc * inv[row].
__global__ __launch_bounds__(512, 2) void gemm2_8p(const u16* __restrict__ A,
                                                   const u16* __restrict__ B,
                                                   float* __restrict__ Cv,
                                                   const float* __restrict__ inv,
                                                   int K, int ldc) {
  constexpr int BM = 128;
  constexpr int MF = 4, MH = 2, LA = 2, NU = 3;
  constexpr int ABUF = BM * 128;
  constexpr int BBUF = 32768;
  constexpr int BUFSZ = ABUF + BBUF;
  __shared__ __align__(1024) char smem[2 * BUFSZ];

  const int tid = threadIdx.x;
  const int lane = tid & 63, wave = tid >> 6;
  const int wr = wave >> 2, wc = wave & 3;
  const int lan15 = lane & 15, g = lane >> 4, l7 = lane & 7;

  const int nwg = gridDim.x;
  const int wg = (blockIdx.x & 7) * (nwg >> 3) + (blockIdx.x >> 3);
  const int bm0 = (wg & 63) * BM;
  const int bn0 = (wg >> 6) * 256;

  const int sr = tid >> 3;
  const int scb = ((tid & 7) ^ (sr & 7)) * 8;
  const u16* Ags = A + (size_t)(bm0 + sr) * K + scb;
  const u16* Bgs = B + (size_t)(bn0 + sr) * K + scb;

  const int sa0 = ((0 + g) ^ l7) * 16;
  const int sa1 = ((4 + g) ^ l7) * 16;
  const int abase = (wr * (BM / 2) + lan15) * 128;
  const int bbase = ABUF + (wc * 64 + lan15) * 128;

  f32x4 acc[MF][4];
#pragma unroll
  for (int m = 0; m < MF; ++m)
#pragma unroll
    for (int n = 0; n < 4; ++n) acc[m][n] = f32x4{0.f, 0.f, 0.f, 0.f};

  const int nt = K >> 6;
  const int niter = nt >> 1;

  auto ISSUE_UNIT = [&](int t, int u) {
    const int bb = (t & 1) * BUFSZ;
    const size_t ko = (size_t)t * 64;
    if (2 * u < LA) {
#pragma unroll
      for (int s = 0; s < 2; ++s) {
        const int j = 2 * u + s;
        __builtin_amdgcn_global_load_lds((as1p)(Ags + (size_t)j * 64 * K + ko),
                                         (as3p)(smem + bb + j * 8192 + tid * 16), 16, 0, 0);
      }
    } else {
#pragma unroll
      for (int s = 0; s < 2; ++s) {
        const int j = 2 * u - LA + s;
        __builtin_amdgcn_global_load_lds((as1p)(Bgs + (size_t)j * 64 * K + ko),
                                         (as3p)(smem + bb + ABUF + j * 8192 + tid * 16), 16, 0, 0);
      }
    }
  };

  bf16x8 a[MH][2], b[4][2];
  auto DS_A = [&](int bb, int mh) {
#pragma unroll
    for (int m = 0; m < MH; ++m) {
      a[m][0] = *(const bf16x8*)(smem + bb + abase + (mh * MH + m) * 2048 + sa0);
      a[m][1] = *(const bf16x8*)(smem + bb + abase + (mh * MH + m) * 2048 + sa1);
    }
  };
  auto DS_B = [&](int bb, int nh) {
#pragma unroll
    for (int n = 0; n < 2; ++n) {
      b[nh * 2 + n][0] = *(const bf16x8*)(smem + bb + bbase + (nh * 2 + n) * 2048 + sa0);
      b[nh * 2 + n][1] = *(const bf16x8*)(smem + bb + bbase + (nh * 2 + n) * 2048 + sa1);
    }
  };
  auto MMA = [&](int mh, int nh) {
    __builtin_amdgcn_s_setprio(1);
#pragma unroll
    for (int m = 0; m < MH; ++m)
#pragma unroll
      for (int n = 0; n < 2; ++n)
#pragma unroll
        for (int ks = 0; ks < 2; ++ks)
          acc[mh * MH + m][nh * 2 + n] = __builtin_amdgcn_mfma_f32_16x16x32_bf16(
              a[m][ks], b[nh * 2 + n][ks], acc[mh * MH + m][nh * 2 + n], 0, 0, 0);
    __builtin_amdgcn_s_setprio(0);
  };

#pragma unroll
  for (int u = 0; u < NU; ++u) ISSUE_UNIT(0, u);
  ISSUE_UNIT(1, 0);
  VM(2);
  BAR();

  for (int i = 0; i < niter; ++i) {
    const int t0 = 2 * i;
    const bool more = (i + 1 < niter);

    DS_A(0, 0); DS_B(0, 0);
    ISSUE_UNIT(t0 + 1, 1);
    BAR(); MMA(0, 0); BAR();

    DS_B(0, 1);
    ISSUE_UNIT(t0 + 1, 2);
    BAR(); MMA(0, 1); BAR();

    DS_A(0, 1);
    BAR(); MMA(1, 0); LGKM0(); BAR();

    if (more) ISSUE_UNIT(t0 + 2, 0);
    BAR(); MMA(1, 1);
    if (more) { VM(2); } else { VM(0); }
    BAR();

    DS_A(BUFSZ, 0); DS_B(BUFSZ, 0);
    if (more) ISSUE_UNIT(t0 + 2, 1);
    BAR(); MMA(0, 0); BAR();

    DS_B(BUFSZ, 1);
    if (more) ISSUE_UNIT(t0 + 2, 2);
    BAR(); MMA(0, 1); BAR();

    DS_A(BUFSZ, 1);
    BAR(); MMA(1, 0); LGKM0(); BAR();

    if (more) ISSUE_UNIT(t0 + 3, 0);
    BAR(); MMA(1, 1);
    if (more) { VM(2); } else { VM(0); }
    BAR();
  }

  const int c0 = bn0 + wc * 64 + lan15;
#pragma unroll
  for (int m = 0; m < MF; ++m)
#pragma unroll
    for (int r = 0; r < 4; ++r) {
      const int row = bm0 + wr * (BM / 2) + m * 16 + g * 4 + r;
      const float iv = inv ? inv[row] : 1.0f;
#pragma unroll
      for (int n = 0; n < 4; ++n)
        Cv[(size_t)row * ldc + c0 + n * 16] = acc[m][n][r] * iv;
    }
}

// ---------------- inv[row] = 1 / sum_j partials[row][j] --------------------
__global__ __launch_bounds__(256) void rowinv(const float* __restrict__ partials,
                                              float* __restrict__ inv) {
  const int row = blockIdx.x * 256 + threadIdx.x;
  const float4* p = (const float4*)(partials + (size_t)row * 128);
  float s = 0.f;
#pragma unroll
  for (int j = 0; j < 32; ++j) {
    float4 v = p[j];
    s += (v.x + v.y) + (v.z + v.w);
  }
  inv[row] = 1.0f / s;
}

// --------------- fallback: normalize E rows in place (bf16) ----------------
__global__ __launch_bounds__(256) void normalize_inplace(u16* __restrict__ E) {
  __shared__ float red[4];
  u16* row = E + (size_t)blockIdx.x * 8192;
  const int tid = threadIdx.x;
  float f[32];
  float s = 0.f;
#pragma unroll
  for (int c = 0; c < 4; ++c) {
    uint4 v = *((const uint4*)row + c * 256 + tid);
    unsigned u[4] = {v.x, v.y, v.z, v.w};
#pragma unroll
    for (int q = 0; q < 4; ++q) {
      f[c * 8 + q * 2] = bf2f((u16)(u[q] & 0xffffu));
      f[c * 8 + q * 2 + 1] = bf2f((u16)(u[q] >> 16));
      s += f[c * 8 + q * 2] + f[c * 8 + q * 2 + 1];
    }
  }
#pragma unroll
  for (int off = 32; off; off >>= 1) s += __shfl_xor(s, off, 64);
  if ((tid & 63) == 0) red[tid >> 6] = s;
  __syncthreads();
  const float iv = 1.0f / ((red[0] + red[1]) + (red[2] + red[3]));
#pragma unroll
  for (int c = 0; c < 4; ++c) {
    uint4 o;
    o.x = pack2(f[c * 8 + 0] * iv, f[c * 8 + 1] * iv);
    o.y = pack2(f[c * 8 + 2] * iv, f[c * 8 + 3] * iv);
    o.z = pack2(f[c * 8 + 4] * iv, f[c * 8 + 5] * iv);
    o.w = pack2(f[c * 8 + 6] * iv, f[c * 8 + 7] * iv);
    *((uint4*)row + c * 256 + tid) = o;
  }
}

// ---------------------------------------------------------------------------
extern "C" void kernel_launch(void* const* d_in, const int* in_sizes, int n_in,
                              void* d_out, int out_size, void* d_ws, size_t ws_size,
                              hipStream_t stream) {
  const float* Q = (const float*)d_in[0];
  const float* K = (const float*)d_in[1];
  const float* V = (const float*)d_in[2];

  char* ws = (char*)d_ws;
  u16* S = (u16*)ws;                                              // 128 MB
  u16* VT = (u16*)(ws + (size_t)134217728);                       // 16 MB
  float* partials = (float*)(ws + (size_t)134217728 + 16777216);  // 4 MB
  float* inv = (float*)(ws + (size_t)134217728 + 16777216 + 4194304);
  const bool haveInv =
      ws_size >= (size_t)134217728 + 16777216 + 4194304 + 32768;

  u16* Qb = (u16*)d_out;   // bf16 Q scratch (16 MB)
  u16* Kb = Qb + 8388608;  // bf16 K scratch (16 MB)

  cvt_bf16<<<4096, 256, 0, stream>>>(Q, Qb);
  cvt_bf16<<<4096, 256, 0, stream>>>(K, Kb);
  transpose_bf16<<<dim3(128, 16), 256, 0, stream>>>(V, VT);

  // E = exp(Q K^T / 32)  [8192 x 8192] bf16 ; grid 1024, 2 blocks/CU
  gemm1_bk32<<<1024, 512, 0, stream>>>(
      Qb, Kb, S, haveInv ? partials : (float*)(ws + 134217728 + 16777216),
      1.0f / 32.0f);

  if (haveInv) {
    rowinv<<<32, 256, 0, stream>>>(partials, inv);
    // O = diag(inv) E V  [8192 x 1024] f32 ; grid 256
    gemm2_8p<<<256, 512, 0, stream>>>(S, VT, (float*)d_out, inv, 8192, 1024);
  } else {
    normalize_inplace<<<8192, 256, 0, stream>>>(S);
    gemm2_8p<<<256, 512, 0, stream>>>(S, VT, (float*)d_out, nullptr, 8192, 1024);
  }
}

// Round 8
// 320.697 us; speedup vs baseline: 4.0773x; 4.0773x over previous
//
#include <hip/hip_runtime.h>
#include <hip/hip_bf16.h>

// ---------------------------------------------------------------------------
// attention via: E = exp(QK^T/32) (bf16), inv[r] = 1/sum_k E[r,k] (per-wave
// partials), O = diag(inv)*E*V.
// Both GEMMs: minimal-barrier FREE-RUN schedule. Per K-tile:
//   [all 24/16 ds_reads up-front + 4 MFMA clusters, free-run]   <- waves
//   LGKM0 ; BAR                 (all waves done reading buf t)      stagger,
//   ISSUE all loads for t+2     (full-tile issue->wait distance)    LDS+MFMA
//   VM(LPT) ; BAR               (t+1 landed; t+2 stays in flight)   overlap
// Only 2 barriers per K-tile (was 8). Counted vmcnt never drains mid-loop.
// T2 both-sides XOR swizzle (0 conflicts), T1 supertile / bm-fastest decode
// (FETCH 98MB verified), T5 setprio per MFMA cluster.
// ws: [0,128MB)=E ; [128MB,144MB)=V^T ; [144MB,148MB)=partials ; then inv.
// d_out holds bf16 Q|K scratch until GEMM2 overwrites it.
// ---------------------------------------------------------------------------

typedef __bf16 bf16x8 __attribute__((ext_vector_type(8)));
typedef float f32x4 __attribute__((ext_vector_type(4)));
typedef const __attribute__((address_space(1))) unsigned int* as1p;
typedef __attribute__((address_space(3))) unsigned int* as3p;
typedef unsigned short u16;

__device__ __forceinline__ u16 f2bf(float x) {
  unsigned u = __float_as_uint(x);
  u += 0x7fffu + ((u >> 16) & 1u);
  return (u16)(u >> 16);
}
__device__ __forceinline__ float bf2f(u16 b) { return __uint_as_float(((unsigned)b) << 16); }
__device__ __forceinline__ unsigned pack2(float lo, float hi) {
  return (unsigned)f2bf(lo) | ((unsigned)f2bf(hi) << 16);
}

#define BAR()   do { __builtin_amdgcn_s_barrier(); asm volatile("" ::: "memory"); } while (0)
#define LGKM0() do { asm volatile("s_waitcnt lgkmcnt(0)" ::: "memory"); __builtin_amdgcn_sched_barrier(0); } while (0)
#define VM(n)   do { asm volatile("s_waitcnt vmcnt(" #n ")" ::: "memory"); __builtin_amdgcn_sched_barrier(0); } while (0)

// --------------------------- f32 -> bf16 convert ---------------------------
__global__ __launch_bounds__(256) void cvt_bf16(const float* __restrict__ in,
                                                unsigned short* __restrict__ out) {
  const size_t i = (size_t)blockIdx.x * 256 + threadIdx.x;
  const float4* p = (const float4*)in + i * 2;
  float4 a = p[0], b = p[1];
  uint4 o;
  o.x = pack2(a.x, a.y);
  o.y = pack2(a.z, a.w);
  o.z = pack2(b.x, b.y);
  o.w = pack2(b.z, b.w);
  ((uint4*)out)[i] = o;
}

// ------------- V [8192,1024] f32 -> V^T [1024,8192] bf16 -------------------
__global__ __launch_bounds__(256) void transpose_bf16(const float* __restrict__ V,
                                                      unsigned short* __restrict__ VT) {
  __shared__ float t[64][65];
  const int rb = blockIdx.x * 64;
  const int cb = blockIdx.y * 64;
  const int tid = threadIdx.x;
#pragma unroll
  for (int it = 0; it < 4; ++it) {
    int r = it * 16 + (tid >> 4);
    int c = (tid & 15) * 4;
    float4 x = *(const float4*)(V + (size_t)(rb + r) * 1024 + cb + c);
    t[r][c] = x.x; t[r][c + 1] = x.y; t[r][c + 2] = x.z; t[r][c + 3] = x.w;
  }
  __syncthreads();
  const int j = tid & 63;
  const int c0 = (tid >> 6) * 16;
#pragma unroll
  for (int i = 0; i < 16; ++i) {
    int c = c0 + i;
    VT[(size_t)(cb + c) * 8192 + rb + j] = f2bf(t[j][c]);
  }
}

// ---------------------- free-run NT GEMM (2 barriers/tile) -----------------
// C[M,N](ldc) = A[M,K]*B[N,K]^T, BN=256. 512 threads, 8 waves (2M x 4N).
// DEC 0: grid 1024 = supertile 16bm x 8bn per XCD chunk   [GEMM1]
// DEC 1: grid 256  = bm-fastest, VT quadrant L2-resident  [GEMM2]
// OUTMODE 0: C=bf16 exp(acc*scale) + per-wave row partials.
// OUTMODE 1: C=f32 acc*inv[row].
template <int BM, int OUTMODE, int DEC>
__global__ __launch_bounds__(512, 2) void gemm_fr(const u16* __restrict__ A,
                                                  const u16* __restrict__ B,
                                                  void* __restrict__ Cv,
                                                  const float* __restrict__ inv,
                                                  float* __restrict__ partials,
                                                  int K, int ldc, float scale) {
  constexpr int MF = BM / 32;       // per-wave m-frags (8 or 4)
  constexpr int MH = MF / 2;        // m-frags per half
  constexpr int LA = BM / 64;       // A gload/thread per K-tile (4 or 2)
  constexpr int LB = 4;             // B gload/thread per K-tile
  constexpr int LPT = LA + LB;      // loads per thread per K-tile (8 or 6)
  constexpr int ABUF = BM * 128;
  constexpr int BBUF = 32768;
  constexpr int BUFSZ = ABUF + BBUF;
  __shared__ __align__(1024) char smem[2 * BUFSZ];

  const int tid = threadIdx.x;
  const int lane = tid & 63, wave = tid >> 6;
  const int wr = wave >> 2, wc = wave & 3;
  const int lan15 = lane & 15, g = lane >> 4, l7 = lane & 7;

  // T1: bijective XCD swizzle (nwg % 8 == 0 at both call sites)
  const int nwg = gridDim.x;
  const int wg = (blockIdx.x & 7) * (nwg >> 3) + (blockIdx.x >> 3);

  int bm0, bn0;
  if constexpr (DEC == 0) {
    const int r = wg & 255;
    bm0 = (r >> 3) * 256;
    bn0 = (((wg >> 8) << 3) | (r & 7)) * 256;
  } else {
    bm0 = (wg & 63) * BM;
    bn0 = (wg >> 6) * 256;
  }

  // staging: thread -> row (tid>>3), swizzled src col-block (tid&7)^(row&7)
  const int sr = tid >> 3;
  const int scb = ((tid & 7) ^ (sr & 7)) * 8;
  const u16* Ags = A + (size_t)(bm0 + sr) * K + scb;
  const u16* Bgs = B + (size_t)(bn0 + sr) * K + scb;

  // fragment-read swizzled 16B-slot offsets
  const int sa0 = ((0 + g) ^ l7) * 16;
  const int sa1 = ((4 + g) ^ l7) * 16;
  const int abase = (wr * (BM / 2) + lan15) * 128;
  const int bbase = ABUF + (wc * 64 + lan15) * 128;

  f32x4 acc[MF][4];
#pragma unroll
  for (int m = 0; m < MF; ++m)
#pragma unroll
    for (int n = 0; n < 4; ++n) acc[m][n] = f32x4{0.f, 0.f, 0.f, 0.f};

  const int nt = K >> 6;  // K-tiles

  auto ISSUE = [&](int t) {  // all LPT loads of tile t, front-loaded
    const int bb = (t & 1) * BUFSZ;
    const size_t ko = (size_t)t * 64;
#pragma unroll
    for (int j = 0; j < LA; ++j)
      __builtin_amdgcn_global_load_lds((as1p)(Ags + (size_t)j * 64 * K + ko),
                                       (as3p)(smem + bb + j * 8192 + tid * 16), 16, 0, 0);
#pragma unroll
    for (int j = 0; j < LB; ++j)
      __builtin_amdgcn_global_load_lds((as1p)(Bgs + (size_t)j * 64 * K + ko),
                                       (as3p)(smem + bb + ABUF + j * 8192 + tid * 16), 16, 0, 0);
  };

  // prologue: tiles 0 and 1 staged; wait tile 0 (tile 1 stays in flight)
  ISSUE(0);
  ISSUE(1);
  if constexpr (LPT == 8) { VM(8); } else { VM(6); }
  BAR();

  for (int t = 0; t < nt; ++t) {
    const char* bp = smem + (t & 1) * BUFSZ;

    // ---- free-run region: all ds_reads up-front, 4 MFMA clusters ----------
    bf16x8 a0[MH][2], b0[4][2], a1[MH][2];
#pragma unroll
    for (int m = 0; m < MH; ++m) {
      a0[m][0] = *(const bf16x8*)(bp + abase + m * 2048 + sa0);
      a0[m][1] = *(const bf16x8*)(bp + abase + m * 2048 + sa1);
    }
#pragma unroll
    for (int n = 0; n < 4; ++n) {
      b0[n][0] = *(const bf16x8*)(bp + bbase + n * 2048 + sa0);
      b0[n][1] = *(const bf16x8*)(bp + bbase + n * 2048 + sa1);
    }
#pragma unroll
    for (int m = 0; m < MH; ++m) {
      a1[m][0] = *(const bf16x8*)(bp + abase + (MH + m) * 2048 + sa0);
      a1[m][1] = *(const bf16x8*)(bp + abase + (MH + m) * 2048 + sa1);
    }

    __builtin_amdgcn_s_setprio(1);
#pragma unroll
    for (int m = 0; m < MH; ++m)
#pragma unroll
      for (int n = 0; n < 2; ++n)
#pragma unroll
        for (int ks = 0; ks < 2; ++ks)
          acc[m][n] = __builtin_amdgcn_mfma_f32_16x16x32_bf16(a0[m][ks], b0[n][ks], acc[m][n], 0, 0, 0);
#pragma unroll
    for (int m = 0; m < MH; ++m)
#pragma unroll
      for (int n = 0; n < 2; ++n)
#pragma unroll
        for (int ks = 0; ks < 2; ++ks)
          acc[m][2 + n] = __builtin_amdgcn_mfma_f32_16x16x32_bf16(a0[m][ks], b0[2 + n][ks], acc[m][2 + n], 0, 0, 0);
#pragma unroll
    for (int m = 0; m < MH; ++m)
#pragma unroll
      for (int n = 0; n < 2; ++n)
#pragma unroll
        for (int ks = 0; ks < 2; ++ks)
          acc[MH + m][n] = __builtin_amdgcn_mfma_f32_16x16x32_bf16(a1[m][ks], b0[n][ks], acc[MH + m][n], 0, 0, 0);
#pragma unroll
    for (int m = 0; m < MH; ++m)
#pragma unroll
      for (int n = 0; n < 2; ++n)
#pragma unroll
        for (int ks = 0; ks < 2; ++ks)
          acc[MH + m][2 + n] = __builtin_amdgcn_mfma_f32_16x16x32_bf16(a1[m][ks], b0[2 + n][ks], acc[MH + m][2 + n], 0, 0, 0);
    __builtin_amdgcn_s_setprio(0);

    // ---- sync 1: all waves finished reading buf(t) ------------------------
    LGKM0();
    BAR();

    // ---- stage tile t+2 into buf(t); wait tile t+1 (t+2 stays in flight) --
    const bool st = (t + 2 < nt);
    if (st) ISSUE(t + 2);
    if (t + 1 < nt) {
      if (st) {
        if constexpr (LPT == 8) { VM(8); } else { VM(6); }
      } else {
        VM(0);
      }
    }
    BAR();
  }

  // ---- epilogue. C/D map: col = lane&15, row = (lane>>4)*4 + reg
  const int c0 = bn0 + wc * 64 + lan15;
  if constexpr (OUTMODE == 0) {
    u16* C = (u16*)Cv;
    const int cb4 = (bn0 >> 8) * 4 + wc;  // partial-column index (0..127)
#pragma unroll
    for (int m = 0; m < MF; ++m)
#pragma unroll
      for (int r = 0; r < 4; ++r) {
        const int row = bm0 + wr * (BM / 2) + m * 16 + g * 4 + r;
        float part = 0.f;
#pragma unroll
        for (int n = 0; n < 4; ++n) {
          float v = __expf(acc[m][n][r] * scale);
          C[(size_t)row * ldc + c0 + n * 16] = f2bf(v);
          part += v;
        }
        part += __shfl_xor(part, 1, 64);
        part += __shfl_xor(part, 2, 64);
        part += __shfl_xor(part, 4, 64);
        part += __shfl_xor(part, 8, 64);
        if (lan15 == 0) partials[(size_t)row * 128 + cb4] = part;
      }
  } else {
    float* C = (float*)Cv;
#pragma unroll
    for (int m = 0; m < MF; ++m)
#pragma unroll
      for (int r = 0; r < 4; ++r) {
        const int row = bm0 + wr * (BM / 2) + m * 16 + g * 4 + r;
        const float iv = inv ? inv[row] : 1.0f;
#pragma unroll
        for (int n = 0; n < 4; ++n)
          C[(size_t)row * ldc + c0 + n * 16] = acc[m][n][r] * iv;
      }
  }
}

// ---------------- inv[row] = 1 / sum_j partials[row][j] --------------------
__global__ __launch_bounds__(256) void rowinv(const float* __restrict__ partials,
                                              float* __restrict__ inv) {
  const int row = blockIdx.x * 256 + threadIdx.x;
  const float4* p = (const float4*)(partials + (size_t)row * 128);
  float s = 0.f;
#pragma unroll
  for (int j = 0; j < 32; ++j) {
    float4 v = p[j];
    s += (v.x + v.y) + (v.z + v.w);
  }
  inv[row] = 1.0f / s;
}

// --------------- fallback: normalize E rows in place (bf16) ----------------
__global__ __launch_bounds__(256) void normalize_inplace(u16* __restrict__ E) {
  __shared__ float red[4];
  u16* row = E + (size_t)blockIdx.x * 8192;
  const int tid = threadIdx.x;
  float f[32];
  float s = 0.f;
#pragma unroll
  for (int c = 0; c < 4; ++c) {
    uint4 v = *((const uint4*)row + c * 256 + tid);
    unsigned u[4] = {v.x, v.y, v.z, v.w};
#pragma unroll
    for (int q = 0; q < 4; ++q) {
      f[c * 8 + q * 2] = bf2f((u16)(u[q] & 0xffffu));
      f[c * 8 + q * 2 + 1] = bf2f((u16)(u[q] >> 16));
      s += f[c * 8 + q * 2] + f[c * 8 + q * 2 + 1];
    }
  }
#pragma unroll
  for (int off = 32; off; off >>= 1) s += __shfl_xor(s, off, 64);
  if ((tid & 63) == 0) red[tid >> 6] = s;
  __syncthreads();
  const float iv = 1.0f / ((red[0] + red[1]) + (red[2] + red[3]));
#pragma unroll
  for (int c = 0; c < 4; ++c) {
    uint4 o;
    o.x = pack2(f[c * 8 + 0] * iv, f[c * 8 + 1] * iv);
    o.y = pack2(f[c * 8 + 2] * iv, f[c * 8 + 3] * iv);
    o.z = pack2(f[c * 8 + 4] * iv, f[c * 8 + 5] * iv);
    o.w = pack2(f[c * 8 + 6] * iv, f[c * 8 + 7] * iv);
    *((uint4*)row + c * 256 + tid) = o;
  }
}

// ---------------------------------------------------------------------------
extern "C" void kernel_launch(void* const* d_in, const int* in_sizes, int n_in,
                              void* d_out, int out_size, void* d_ws, size_t ws_size,
                              hipStream_t stream) {
  const float* Q = (const float*)d_in[0];
  const float* K = (const float*)d_in[1];
  const float* V = (const float*)d_in[2];

  char* ws = (char*)d_ws;
  u16* S = (u16*)ws;                                              // 128 MB
  u16* VT = (u16*)(ws + (size_t)134217728);                       // 16 MB
  float* partials = (float*)(ws + (size_t)134217728 + 16777216);  // 4 MB
  float* inv = (float*)(ws + (size_t)134217728 + 16777216 + 4194304);
  const bool haveInv =
      ws_size >= (size_t)134217728 + 16777216 + 4194304 + 32768;

  u16* Qb = (u16*)d_out;   // bf16 Q scratch (16 MB)
  u16* Kb = Qb + 8388608;  // bf16 K scratch (16 MB)

  cvt_bf16<<<4096, 256, 0, stream>>>(Q, Qb);
  cvt_bf16<<<4096, 256, 0, stream>>>(K, Kb);
  transpose_bf16<<<dim3(128, 16), 256, 0, stream>>>(V, VT);

  // E = exp(Q K^T / 32)  [8192 x 8192] bf16 ; grid 1024
  gemm_fr<256, 0, 0><<<1024, 512, 0, stream>>>(
      Qb, Kb, S, nullptr, haveInv ? partials : (float*)(ws + 134217728 + 16777216),
      1024, 8192, 1.0f / 32.0f);

  if (haveInv) {
    rowinv<<<32, 256, 0, stream>>>(partials, inv);
    // O = diag(inv) E V  [8192 x 1024] f32 ; grid 256
    gemm_fr<128, 1, 1><<<256, 512, 0, stream>>>(
        S, VT, d_out, inv, nullptr, 8192, 1024, 1.0f);
  } else {
    normalize_inplace<<<8192, 256, 0, stream>>>(S);
    gemm_fr<128, 1, 1><<<256, 512, 0, stream>>>(
        S, VT, d_out, nullptr, nullptr, 8192, 1024, 1.0f);
  }
}